// Round 3
// baseline (383.719 us; speedup 1.0000x reference)
//
#include <hip/hip_runtime.h>
#include <hip/hip_bf16.h>

#define B_ 16
#define I_ 256
#define O_ 256
#define T_ 512
#define L_ 8192
#define K_ 7
#define PAD_ 3
#define BN 64
#define NT 4      // l-tiles per block, pipelined producer/consumer
#define LDK 264   // X_lds row stride in bf16 elements (256 + 8 pad)

typedef unsigned short u16;
typedef unsigned int u32;
typedef __attribute__((ext_vector_type(8))) short short8;
typedef __attribute__((ext_vector_type(4))) float f32x4;

__device__ inline u16 f2bf(float f) {
    union { float f; u32 u; } v; v.f = f;
    u32 r = v.u + 0x7FFF + ((v.u >> 16) & 1);   // RNE
    return (u16)(r >> 16);
}

// ---------------- Kernel 1: mod[b][i] = t[b,:] . mod_w[i,:] + mod_b[i] ----------------
__global__ void mod_kernel(const float* __restrict__ t, const float* __restrict__ mod_w,
                           const float* __restrict__ mod_b, float* __restrict__ mod) {
    int g = blockIdx.x, b = blockIdx.y;
    int lane = threadIdx.x & 63, wv = threadIdx.x >> 6;
    const float* tb = t + b * T_;
    #pragma unroll
    for (int q = 0; q < 4; ++q) {
        int i = g * 16 + wv * 4 + q;
        const float* wr = mod_w + (size_t)i * T_;
        float s = 0.f;
        #pragma unroll
        for (int u = 0; u < 8; ++u) s += wr[lane + u * 64] * tb[lane + u * 64];
        #pragma unroll
        for (int d = 32; d; d >>= 1) s += __shfl_down(s, d);
        if (lane == 0) mod[b * I_ + i] = s + mod_b[i];
    }
}

// ---------------- Kernel 2: Wb[b][o][i] = bf16( proj_w[o,i]*(mod[b,i]+1) * demod[b,o] ) ----
__global__ void wmod_kernel(const float* __restrict__ proj_w, const float* __restrict__ mod,
                            u16* __restrict__ Wb) {
    int og = blockIdx.x, b = blockIdx.y;
    int lane = threadIdx.x & 63, wv = threadIdx.x >> 6;
    const float* mrow = mod + b * I_;
    #pragma unroll
    for (int q = 0; q < 4; ++q) {
        int o = og * 16 + wv * 4 + q;
        const float* pw = proj_w + (size_t)o * I_;
        float4 pv = *(const float4*)(pw + lane * 4);
        float4 mv = *(const float4*)(mrow + lane * 4);
        float v0 = pv.x * (mv.x + 1.f);
        float v1 = pv.y * (mv.y + 1.f);
        float v2 = pv.z * (mv.z + 1.f);
        float v3 = pv.w * (mv.w + 1.f);
        float ss = v0*v0 + v1*v1 + v2*v2 + v3*v3;
        #pragma unroll
        for (int d = 32; d; d >>= 1) ss += __shfl_xor(ss, d);
        float dem = rsqrtf(ss + 1e-8f);
        u32 lo = (u32)f2bf(v0 * dem) | ((u32)f2bf(v1 * dem) << 16);
        u32 hi = (u32)f2bf(v2 * dem) | ((u32)f2bf(v3 * dem) << 16);
        *(uint2*)(Wb + (size_t)(b * O_ + o) * I_ + lane * 4) = make_uint2(lo, hi);
    }
}

// ---------------- Kernel 3: producer/consumer fused conv + batched GEMM ----------------
// 512 threads = 8 waves. Waves 0-3: depthwise conv -> Xs[buf]. Waves 4-7: GEMM+store
// from Xs[buf^1]. Pipelined over NT=4 consecutive l-tiles; double-buffered LDS.
// grid (L/(BN*NT)=32, 16 b) = 512 blocks = 2 resident/CU (LDS 2x33.8KB, regs capped 128).
__global__ __launch_bounds__(512, 4) void main_kernel(
    const float* __restrict__ bx, const float* __restrict__ conv_w,
    const u16* __restrict__ Wb, const float* __restrict__ proj_b,
    float* __restrict__ out)
{
    __shared__ __align__(16) u16 Xs[2][BN * LDK];   // 67,584 B

    const int b = blockIdx.y;
    const int tg0 = blockIdx.x * NT;      // first l-tile this block owns
    const int tid = threadIdx.x;
    const int wv = tid >> 6;
    const bool producer = (wv < 4);

    if (producer) {
        // ---- conv producer: tid in [0,256) owns 4 channels, sweeps 16 l per iter ----
        const int rq = tid >> 2;          // 0..63 -> i0 = 4*rq
        const int lq = tid & 3;           // 0..3
        const int i0 = rq * 4;
        const float* bxr = bx + (size_t)b * I_ * L_;

        float wr[4][K_];
        #pragma unroll
        for (int di = 0; di < 4; ++di)
            #pragma unroll
            for (int j = 0; j < K_; ++j)
                wr[di][j] = conv_w[(i0 + di) * K_ + j];

        for (int tt = 0; tt < NT; ++tt) {
            const int l0 = (tg0 + tt) * BN;
            u16* xsb = Xs[tt & 1];
            const bool interior = (l0 >= 4) && (l0 + 72 <= L_);

            for (int it = 0; it < 4; ++it) {
                const int lb = it * 16 + lq * 4;   // 0..60
                u16 hv[4][4];                      // [dl][di]
                #pragma unroll
                for (int di = 0; di < 4; ++di) {
                    const float* row = bxr + (size_t)(i0 + di) * L_ + l0;
                    float x[12];                   // window [lb-4, lb+12)
                    if (interior) {
                        const float4* rp = (const float4*)(row + lb - 4);
                        float4 w0 = rp[0], w1 = rp[1], w2 = rp[2];
                        x[0]=w0.x; x[1]=w0.y; x[2]=w0.z; x[3]=w0.w;
                        x[4]=w1.x; x[5]=w1.y; x[6]=w1.z; x[7]=w1.w;
                        x[8]=w2.x; x[9]=w2.y; x[10]=w2.z; x[11]=w2.w;
                    } else {
                        #pragma unroll
                        for (int w = 0; w < 12; ++w) {
                            int p = l0 + lb - 4 + w;
                            x[w] = (p >= 0 && p < L_) ? row[lb - 4 + w] : 0.f;
                        }
                    }
                    #pragma unroll
                    for (int dl = 0; dl < 4; ++dl) {
                        float a = 0.f;
                        #pragma unroll
                        for (int j = 0; j < K_; ++j) a += wr[di][j] * x[dl + 1 + j];
                        hv[dl][di] = f2bf(a);
                    }
                }
                #pragma unroll
                for (int dl = 0; dl < 4; ++dl) {
                    int n = lb + dl;
                    u32 lo = (u32)hv[dl][0] | ((u32)hv[dl][1] << 16);
                    u32 hi = (u32)hv[dl][2] | ((u32)hv[dl][3] << 16);
                    *(uint2*)(&xsb[n * LDK + i0]) = make_uint2(lo, hi);
                }
            }
            __syncthreads();   // publish buf tt; consumers finished buf tt^1
        }
        // producers done; no more barriers anywhere
    } else {
        // ---- GEMM consumer: ctid in [0,256), wave wg owns output rows [64*wg, 64*wg+64) ----
        const int ctid = tid - 256;
        const int lane = ctid & 63;
        const int wg = ctid >> 6;
        const int mlane = lane & 15;
        const int quad = lane >> 4;
        const u16* Wrow = Wb + (size_t)(b * O_ + wg * 64 + mlane) * I_;
        float* outb = out + (size_t)b * O_ * L_;

        for (int tt = 0; tt < NT; ++tt) {
            if (tt > 0) {
                const int l0 = (tg0 + tt - 1) * BN;
                const u16* xsb = Xs[(tt - 1) & 1];

                f32x4 acc[4][4];
                #pragma unroll
                for (int r = 0; r < 4; ++r)
                    #pragma unroll
                    for (int c = 0; c < 4; ++c)
                        acc[r][c] = (f32x4){0.f, 0.f, 0.f, 0.f};

                for (int kb = 0; kb < 8; ++kb) {
                    const int koff = kb * 32 + quad * 8;
                    short8 a[4], bbf[4];
                    #pragma unroll
                    for (int r = 0; r < 4; ++r)
                        a[r] = *(const short8*)(Wrow + r * 16 * I_ + koff);
                    #pragma unroll
                    for (int c = 0; c < 4; ++c)
                        bbf[c] = *(const short8*)(&xsb[(c * 16 + mlane) * LDK + koff]);
                    #pragma unroll
                    for (int r = 0; r < 4; ++r)
                        #pragma unroll
                        for (int c = 0; c < 4; ++c)
                            acc[r][c] = __builtin_amdgcn_mfma_f32_16x16x32_bf16(a[r], bbf[c], acc[r][c], 0, 0, 0);
                }

                #pragma unroll
                for (int r = 0; r < 4; ++r) {
                    const int obase = wg * 64 + r * 16 + quad * 4;
                    #pragma unroll
                    for (int p = 0; p < 4; ++p) {
                        const int o = obase + p;
                        const float bias = proj_b[o];
                        float* orow = outb + (size_t)o * L_ + l0 + mlane;
                        #pragma unroll
                        for (int c = 0; c < 4; ++c)
                            orow[c * 16] = acc[r][c][p] + bias;
                    }
                }
            }
            __syncthreads();   // buf tt now published by producers
        }

        // final tile (NT-1), produced before the last barrier
        {
            const int l0 = (tg0 + NT - 1) * BN;
            const u16* xsb = Xs[(NT - 1) & 1];

            f32x4 acc[4][4];
            #pragma unroll
            for (int r = 0; r < 4; ++r)
                #pragma unroll
                for (int c = 0; c < 4; ++c)
                    acc[r][c] = (f32x4){0.f, 0.f, 0.f, 0.f};

            for (int kb = 0; kb < 8; ++kb) {
                const int koff = kb * 32 + quad * 8;
                short8 a[4], bbf[4];
                #pragma unroll
                for (int r = 0; r < 4; ++r)
                    a[r] = *(const short8*)(Wrow + r * 16 * I_ + koff);
                #pragma unroll
                for (int c = 0; c < 4; ++c)
                    bbf[c] = *(const short8*)(&xsb[(c * 16 + mlane) * LDK + koff]);
                #pragma unroll
                for (int r = 0; r < 4; ++r)
                    #pragma unroll
                    for (int c = 0; c < 4; ++c)
                        acc[r][c] = __builtin_amdgcn_mfma_f32_16x16x32_bf16(a[r], bbf[c], acc[r][c], 0, 0, 0);
            }

            #pragma unroll
            for (int r = 0; r < 4; ++r) {
                const int obase = wg * 64 + r * 16 + quad * 4;
                #pragma unroll
                for (int p = 0; p < 4; ++p) {
                    const int o = obase + p;
                    const float bias = proj_b[o];
                    float* orow = outb + (size_t)o * L_ + l0 + mlane;
                    #pragma unroll
                    for (int c = 0; c < 4; ++c)
                        orow[c * 16] = acc[r][c][p] + bias;
                }
            }
        }
    }
}

extern "C" void kernel_launch(void* const* d_in, const int* in_sizes, int n_in,
                              void* d_out, int out_size, void* d_ws, size_t ws_size,
                              hipStream_t stream) {
    const float* bx     = (const float*)d_in[0];
    const float* t      = (const float*)d_in[1];
    const float* conv_w = (const float*)d_in[2];
    const float* proj_w = (const float*)d_in[3];
    const float* proj_b = (const float*)d_in[4];
    const float* mod_w  = (const float*)d_in[5];
    const float* mod_b  = (const float*)d_in[6];
    float* out = (float*)d_out;

    float* mod = (float*)d_ws;                       // 16 KB
    u16*   Wb  = (u16*)((char*)d_ws + 16384);        // 256 KB bf16 modulated weights

    mod_kernel<<<dim3(16, 16), 256, 0, stream>>>(t, mod_w, mod_b, mod);
    wmod_kernel<<<dim3(16, 16), 256, 0, stream>>>(proj_w, mod, Wb);
    main_kernel<<<dim3(32, 16), 512, 0, stream>>>(bx, conv_w, Wb, proj_b, out);
}

// Round 9
// 371.413 us; speedup vs baseline: 1.0331x; 1.0331x over previous
//
#include <hip/hip_runtime.h>
#include <hip/hip_bf16.h>

#define B_ 16
#define I_ 256
#define O_ 256
#define T_ 512
#define L_ 8192
#define K_ 7
#define PAD_ 3
#define BN 64
#define LDK 264   // fallback-kernel LDS row stride (256 + 8 pad)

typedef unsigned short u16;
typedef unsigned int u32;
typedef __attribute__((ext_vector_type(8))) short short8;
typedef __attribute__((ext_vector_type(4))) float f32x4;

__device__ inline u16 f2bf(float f) {
    union { float f; u32 u; } v; v.f = f;
    u32 r = v.u + 0x7FFF + ((v.u >> 16) & 1);   // RNE
    return (u16)(r >> 16);
}

// ---------------- Kernel 1: mod[b][i] = t[b,:] . mod_w[i,:] + mod_b[i] ----------------
__global__ void mod_kernel(const float* __restrict__ t, const float* __restrict__ mod_w,
                           const float* __restrict__ mod_b, float* __restrict__ mod) {
    int g = blockIdx.x, b = blockIdx.y;
    int lane = threadIdx.x & 63, wv = threadIdx.x >> 6;
    const float* tb = t + b * T_;
    #pragma unroll
    for (int q = 0; q < 4; ++q) {
        int i = g * 16 + wv * 4 + q;
        const float* wr = mod_w + (size_t)i * T_;
        float s = 0.f;
        #pragma unroll
        for (int u = 0; u < 8; ++u) s += wr[lane + u * 64] * tb[lane + u * 64];
        #pragma unroll
        for (int d = 32; d; d >>= 1) s += __shfl_down(s, d);
        if (lane == 0) mod[b * I_ + i] = s + mod_b[i];
    }
}

// ---------------- Kernel 2: Wb[b][o][i] = bf16( proj_w[o,i]*(mod[b,i]+1) * demod[b,o] ) ----
__global__ void wmod_kernel(const float* __restrict__ proj_w, const float* __restrict__ mod,
                            u16* __restrict__ Wb) {
    int og = blockIdx.x, b = blockIdx.y;
    int lane = threadIdx.x & 63, wv = threadIdx.x >> 6;
    const float* mrow = mod + b * I_;
    #pragma unroll
    for (int q = 0; q < 4; ++q) {
        int o = og * 16 + wv * 4 + q;
        const float* pw = proj_w + (size_t)o * I_;
        float4 pv = *(const float4*)(pw + lane * 4);
        float4 mv = *(const float4*)(mrow + lane * 4);
        float v0 = pv.x * (mv.x + 1.f);
        float v1 = pv.y * (mv.y + 1.f);
        float v2 = pv.z * (mv.z + 1.f);
        float v3 = pv.w * (mv.w + 1.f);
        float ss = v0*v0 + v1*v1 + v2*v2 + v3*v3;
        #pragma unroll
        for (int d = 32; d; d >>= 1) ss += __shfl_xor(ss, d);
        float dem = rsqrtf(ss + 1e-8f);
        u32 lo = (u32)f2bf(v0 * dem) | ((u32)f2bf(v1 * dem) << 16);
        u32 hi = (u32)f2bf(v2 * dem) | ((u32)f2bf(v3 * dem) << 16);
        *(uint2*)(Wb + (size_t)(b * O_ + o) * I_ + lane * 4) = make_uint2(lo, hi);
    }
}

// ---------------- Kernel 3a: depthwise conv stream -> Xc[b][l][i] (bf16) ----------------
// grid (128, 16), 256 thr. No LDS, no barriers. Thread owns 4 channels x 16 l-positions.
// Writes uint2 (4 bf16 along i) -> per store inst: 4 rows x 128B contiguous segments.
__global__ __launch_bounds__(256) void conv_kernel(
    const float* __restrict__ bx, const float* __restrict__ conv_w,
    u16* __restrict__ Xc)
{
    const int tile = blockIdx.x;
    const int b = blockIdx.y;
    const int l0 = tile * BN;
    const int tid = threadIdx.x;
    const int rq = tid >> 2;        // 0..63 -> i0 = 4*rq
    const int lq = tid & 3;         // 0..3
    const int i0 = rq * 4;
    const float* bxr = bx + (size_t)b * I_ * L_;
    u16* xcb = Xc + (size_t)b * L_ * I_;
    const bool interior = (l0 >= 4) && (l0 + 72 <= L_);

    float wr[4][K_];
    #pragma unroll
    for (int di = 0; di < 4; ++di)
        #pragma unroll
        for (int j = 0; j < K_; ++j)
            wr[di][j] = conv_w[(i0 + di) * K_ + j];

    for (int it = 0; it < 4; ++it) {
        const int lb = it * 16 + lq * 4;   // 0..60
        u16 hv[4][4];                      // [dl][di]
        #pragma unroll
        for (int di = 0; di < 4; ++di) {
            const float* row = bxr + (size_t)(i0 + di) * L_ + l0;
            float x[12];                   // window [lb-4, lb+12)
            if (interior) {
                const float4* rp = (const float4*)(row + lb - 4);
                float4 w0 = rp[0], w1 = rp[1], w2 = rp[2];
                x[0]=w0.x; x[1]=w0.y; x[2]=w0.z; x[3]=w0.w;
                x[4]=w1.x; x[5]=w1.y; x[6]=w1.z; x[7]=w1.w;
                x[8]=w2.x; x[9]=w2.y; x[10]=w2.z; x[11]=w2.w;
            } else {
                #pragma unroll
                for (int w = 0; w < 12; ++w) {
                    int p = l0 + lb - 4 + w;
                    x[w] = (p >= 0 && p < L_) ? row[lb - 4 + w] : 0.f;
                }
            }
            #pragma unroll
            for (int dl = 0; dl < 4; ++dl) {
                float a = 0.f;
                #pragma unroll
                for (int j = 0; j < K_; ++j) a += wr[di][j] * x[dl + 1 + j];
                hv[dl][di] = f2bf(a);
            }
        }
        #pragma unroll
        for (int dl = 0; dl < 4; ++dl) {
            u32 lo = (u32)hv[dl][0] | ((u32)hv[dl][1] << 16);
            u32 hi = (u32)hv[dl][2] | ((u32)hv[dl][3] << 16);
            *(uint2*)(xcb + (size_t)(l0 + lb + dl) * I_ + i0) = make_uint2(lo, hi);
        }
    }
}

// ---------------- Kernel 3b: batched GEMM stream out = Wb * Xc + proj_b ----------------
// grid (128, 16), 256 thr = 4 waves. No LDS, no barriers. B-frags direct from global Xc
// ([l][i] layout == MFMA B-frag layout); A-frags from Wb (2MB total, L2-resident).
__global__ __launch_bounds__(256) void gemm_kernel(
    const u16* __restrict__ Xc, const u16* __restrict__ Wb,
    const float* __restrict__ proj_b, float* __restrict__ out)
{
    const int tile = blockIdx.x;
    const int b = blockIdx.y;
    const int l0 = tile * BN;
    const int tid = threadIdx.x;
    const int lane = tid & 63;
    const int wg = tid >> 6;
    const int mlane = lane & 15;
    const int quad = lane >> 4;

    const u16* Wrow = Wb + (size_t)(b * O_ + wg * 64 + mlane) * I_;
    const u16* Xrow = Xc + ((size_t)b * L_ + l0) * I_;

    f32x4 acc[4][4];
    #pragma unroll
    for (int r = 0; r < 4; ++r)
        #pragma unroll
        for (int c = 0; c < 4; ++c)
            acc[r][c] = (f32x4){0.f, 0.f, 0.f, 0.f};

    #pragma unroll
    for (int kb = 0; kb < 8; ++kb) {
        const int koff = kb * 32 + quad * 8;
        short8 a[4], bbf[4];
        #pragma unroll
        for (int r = 0; r < 4; ++r)
            a[r] = *(const short8*)(Wrow + r * 16 * I_ + koff);
        #pragma unroll
        for (int c = 0; c < 4; ++c)
            bbf[c] = *(const short8*)(Xrow + (size_t)(c * 16 + mlane) * I_ + koff);
        #pragma unroll
        for (int r = 0; r < 4; ++r)
            #pragma unroll
            for (int c = 0; c < 4; ++c)
                acc[r][c] = __builtin_amdgcn_mfma_f32_16x16x32_bf16(a[r], bbf[c], acc[r][c], 0, 0, 0);
    }

    float* outb = out + (size_t)b * O_ * L_;
    #pragma unroll
    for (int r = 0; r < 4; ++r) {
        const int obase = wg * 64 + r * 16 + quad * 4;
        #pragma unroll
        for (int p = 0; p < 4; ++p) {
            const int o = obase + p;
            const float bias = proj_b[o];
            float* orow = outb + (size_t)o * L_ + l0 + mlane;
            #pragma unroll
            for (int c = 0; c < 4; ++c)
                orow[c * 16] = acc[r][c][p] + bias;
        }
    }
}

// ---------------- Fallback: round-1 fused kernel (used if workspace too small) ----------
__global__ __launch_bounds__(256) void fused_kernel(
    const float* __restrict__ bx, const float* __restrict__ conv_w,
    const u16* __restrict__ Wb, const float* __restrict__ proj_b,
    float* __restrict__ out)
{
    __shared__ __align__(16) u16 Xs[BN * LDK];

    const int tile = blockIdx.x;
    const int b = blockIdx.y;
    const int l0 = tile * BN;
    const int tid = threadIdx.x;
    const int lane = tid & 63;
    const int wv = tid >> 6;
    const int mlane = lane & 15;
    const int quad = lane >> 4;

    const int rq = tid >> 2;
    const int lq = tid & 3;
    const int i0 = rq * 4;
    const float* bxr = bx + (size_t)b * I_ * L_;
    const bool interior = (l0 >= 4) && (l0 + 72 <= L_);

    float wr[4][K_];
    #pragma unroll
    for (int di = 0; di < 4; ++di)
        #pragma unroll
        for (int j = 0; j < K_; ++j)
            wr[di][j] = conv_w[(i0 + di) * K_ + j];

    for (int it = 0; it < 4; ++it) {
        const int lb = it * 16 + lq * 4;
        u16 hv[4][4];
        #pragma unroll
        for (int di = 0; di < 4; ++di) {
            const float* row = bxr + (size_t)(i0 + di) * L_ + l0;
            float x[12];
            if (interior) {
                const float4* rp = (const float4*)(row + lb - 4);
                float4 w0 = rp[0], w1 = rp[1], w2 = rp[2];
                x[0]=w0.x; x[1]=w0.y; x[2]=w0.z; x[3]=w0.w;
                x[4]=w1.x; x[5]=w1.y; x[6]=w1.z; x[7]=w1.w;
                x[8]=w2.x; x[9]=w2.y; x[10]=w2.z; x[11]=w2.w;
            } else {
                #pragma unroll
                for (int w = 0; w < 12; ++w) {
                    int p = l0 + lb - 4 + w;
                    x[w] = (p >= 0 && p < L_) ? row[lb - 4 + w] : 0.f;
                }
            }
            #pragma unroll
            for (int dl = 0; dl < 4; ++dl) {
                float a = 0.f;
                #pragma unroll
                for (int j = 0; j < K_; ++j) a += wr[di][j] * x[dl + 1 + j];
                hv[dl][di] = f2bf(a);
            }
        }
        #pragma unroll
        for (int dl = 0; dl < 4; ++dl) {
            int n = lb + dl;
            u32 lo = (u32)hv[dl][0] | ((u32)hv[dl][1] << 16);
            u32 hi = (u32)hv[dl][2] | ((u32)hv[dl][3] << 16);
            *(uint2*)(&Xs[n * LDK + i0]) = make_uint2(lo, hi);
        }
    }
    __syncthreads();

    f32x4 acc[4][4];
    #pragma unroll
    for (int r = 0; r < 4; ++r)
        #pragma unroll
        for (int c = 0; c < 4; ++c)
            acc[r][c] = (f32x4){0.f, 0.f, 0.f, 0.f};

    const u16* Wrow = Wb + (size_t)(b * O_ + wv * 64 + mlane) * I_;

    for (int kb = 0; kb < 8; ++kb) {
        const int koff = kb * 32 + quad * 8;
        short8 a[4], bbf[4];
        #pragma unroll
        for (int r = 0; r < 4; ++r)
            a[r] = *(const short8*)(Wrow + r * 16 * I_ + koff);
        #pragma unroll
        for (int c = 0; c < 4; ++c)
            bbf[c] = *(const short8*)(&Xs[(c * 16 + mlane) * LDK + koff]);
        #pragma unroll
        for (int r = 0; r < 4; ++r)
            #pragma unroll
            for (int c = 0; c < 4; ++c)
                acc[r][c] = __builtin_amdgcn_mfma_f32_16x16x32_bf16(a[r], bbf[c], acc[r][c], 0, 0, 0);
    }

    float* outb = out + (size_t)b * O_ * L_;
    #pragma unroll
    for (int r = 0; r < 4; ++r) {
        const int obase = wv * 64 + r * 16 + quad * 4;
        #pragma unroll
        for (int p = 0; p < 4; ++p) {
            const int o = obase + p;
            const float bias = proj_b[o];
            float* orow = outb + (size_t)o * L_ + l0 + mlane;
            #pragma unroll
            for (int c = 0; c < 4; ++c)
                orow[c * 16] = acc[r][c][p] + bias;
        }
    }
}

extern "C" void kernel_launch(void* const* d_in, const int* in_sizes, int n_in,
                              void* d_out, int out_size, void* d_ws, size_t ws_size,
                              hipStream_t stream) {
    const float* bx     = (const float*)d_in[0];
    const float* t      = (const float*)d_in[1];
    const float* conv_w = (const float*)d_in[2];
    const float* proj_w = (const float*)d_in[3];
    const float* proj_b = (const float*)d_in[4];
    const float* mod_w  = (const float*)d_in[5];
    const float* mod_b  = (const float*)d_in[6];
    float* out = (float*)d_out;

    float* mod = (float*)d_ws;                         // 16 KB
    u16*   Wb  = (u16*)((char*)d_ws + 16384);          // 2 MB bf16 modulated weights
    u16*   Xc  = (u16*)((char*)d_ws + (4u << 20));     // 64 MiB bf16 conv output [b][l][i]

    const size_t need = (4u << 20) + ((size_t)B_ * L_ * I_ * 2);

    mod_kernel<<<dim3(16, 16), 256, 0, stream>>>(t, mod_w, mod_b, mod);
    wmod_kernel<<<dim3(16, 16), 256, 0, stream>>>(proj_w, mod, Wb);

    if (ws_size >= need) {
        conv_kernel<<<dim3(128, 16), 256, 0, stream>>>(bx, conv_w, Xc);
        gemm_kernel<<<dim3(128, 16), 256, 0, stream>>>(Xc, Wb, proj_b, out);
    } else {
        fused_kernel<<<dim3(128, 16), 256, 0, stream>>>(bx, conv_w, Wb, proj_b, out);
    }
}

// Round 11
// 314.857 us; speedup vs baseline: 1.2187x; 1.1796x over previous
//
#include <hip/hip_runtime.h>
#include <hip/hip_bf16.h>

#define B_ 16
#define I_ 256
#define O_ 256
#define T_ 512
#define L_ 8192
#define K_ 7
#define PAD_ 3
#define BN 64
#define LDK 264   // X_lds row stride in bf16 elements (256 + 8 pad)

typedef unsigned short u16;
typedef unsigned int u32;
typedef __attribute__((ext_vector_type(8))) short short8;
typedef __attribute__((ext_vector_type(4))) float f32x4;

__device__ inline u16 f2bf(float f) {
    union { float f; u32 u; } v; v.f = f;
    u32 r = v.u + 0x7FFF + ((v.u >> 16) & 1);   // RNE
    return (u16)(r >> 16);
}

// ---------------- Kernel 1: mod[b][i] = t[b,:] . mod_w[i,:] + mod_b[i] ----------------
__global__ void mod_kernel(const float* __restrict__ t, const float* __restrict__ mod_w,
                           const float* __restrict__ mod_b, float* __restrict__ mod) {
    int g = blockIdx.x, b = blockIdx.y;
    int lane = threadIdx.x & 63, wv = threadIdx.x >> 6;
    const float* tb = t + b * T_;
    #pragma unroll
    for (int q = 0; q < 4; ++q) {
        int i = g * 16 + wv * 4 + q;
        const float* wr = mod_w + (size_t)i * T_;
        float s = 0.f;
        #pragma unroll
        for (int u = 0; u < 8; ++u) s += wr[lane + u * 64] * tb[lane + u * 64];
        #pragma unroll
        for (int d = 32; d; d >>= 1) s += __shfl_down(s, d);
        if (lane == 0) mod[b * I_ + i] = s + mod_b[i];
    }
}

// ---------------- Kernel 2: Wb[b][o][i] = bf16( proj_w[o,i]*(mod[b,i]+1) * demod[b,o] ) ----
__global__ void wmod_kernel(const float* __restrict__ proj_w, const float* __restrict__ mod,
                            u16* __restrict__ Wb) {
    int og = blockIdx.x, b = blockIdx.y;
    int lane = threadIdx.x & 63, wv = threadIdx.x >> 6;
    const float* mrow = mod + b * I_;
    #pragma unroll
    for (int q = 0; q < 4; ++q) {
        int o = og * 16 + wv * 4 + q;
        const float* pw = proj_w + (size_t)o * I_;
        float4 pv = *(const float4*)(pw + lane * 4);
        float4 mv = *(const float4*)(mrow + lane * 4);
        float v0 = pv.x * (mv.x + 1.f);
        float v1 = pv.y * (mv.y + 1.f);
        float v2 = pv.z * (mv.z + 1.f);
        float v3 = pv.w * (mv.w + 1.f);
        float ss = v0*v0 + v1*v1 + v2*v2 + v3*v3;
        #pragma unroll
        for (int d = 32; d; d >>= 1) ss += __shfl_xor(ss, d);
        float dem = rsqrtf(ss + 1e-8f);
        u32 lo = (u32)f2bf(v0 * dem) | ((u32)f2bf(v1 * dem) << 16);
        u32 hi = (u32)f2bf(v2 * dem) | ((u32)f2bf(v3 * dem) << 16);
        *(uint2*)(Wb + (size_t)(b * O_ + o) * I_ + lane * 4) = make_uint2(lo, hi);
    }
}

// ---------------- Kernel 3: fused depthwise-conv + batched GEMM ----------------
// R1 champion structure (154us) with ONE change: conv phase loads are batched.
// All 12 float4 window loads per it-iteration go to DISTINCT registers (wv[4][3],
// static indexing), issued before any compute -> ~12KB/wave in flight instead of
// serialized load->wait->use chains (R9 diagnosis: 48-96 VGPR forced vmcnt drains,
// capping streaming at ~2.2 TB/s with all pipes idle).
__global__ __launch_bounds__(256) void main_kernel(
    const float* __restrict__ bx, const float* __restrict__ conv_w,
    const u16* __restrict__ Wb, const float* __restrict__ proj_b,
    float* __restrict__ out)
{
    __shared__ __align__(16) u16 Xs[BN * LDK];   // 33,792 B

    const int tile = blockIdx.x;
    const int b = blockIdx.y;
    const int l0 = tile * BN;
    const int tid = threadIdx.x;
    const int lane = tid & 63;
    const int wv = tid >> 6;
    const int mlane = lane & 15;
    const int quad = lane >> 4;

    // ---- Phase 1: depthwise conv (load-all-then-compute-all) ----
    const int rq = tid >> 2;        // 0..63  -> i0 = 4*rq
    const int lq = tid & 3;         // 0..3   -> l offset within iter
    const int i0 = rq * 4;
    const float* bxr = bx + (size_t)b * I_ * L_;
    const bool interior = (l0 >= 4) && (l0 + 72 <= L_);

    float wr[4][K_];
    #pragma unroll
    for (int di = 0; di < 4; ++di)
        #pragma unroll
        for (int j = 0; j < K_; ++j)
            wr[di][j] = conv_w[(i0 + di) * K_ + j];

    const float* row0 = bxr + (size_t)(i0 + 0) * L_ + l0;
    const float* row1 = bxr + (size_t)(i0 + 1) * L_ + l0;
    const float* row2 = bxr + (size_t)(i0 + 2) * L_ + l0;
    const float* row3 = bxr + (size_t)(i0 + 3) * L_ + l0;

    for (int it = 0; it < 4; ++it) {
        const int lb = it * 16 + lq * 4;   // 0..60

        // -- load phase: 12 independent float4 loads into distinct registers --
        float4 wvr[4][3];                  // [di][seg], static indexing only
        if (interior) {
            const float4* rp0 = (const float4*)(row0 + lb - 4);
            const float4* rp1 = (const float4*)(row1 + lb - 4);
            const float4* rp2 = (const float4*)(row2 + lb - 4);
            const float4* rp3 = (const float4*)(row3 + lb - 4);
            wvr[0][0] = rp0[0]; wvr[0][1] = rp0[1]; wvr[0][2] = rp0[2];
            wvr[1][0] = rp1[0]; wvr[1][1] = rp1[1]; wvr[1][2] = rp1[2];
            wvr[2][0] = rp2[0]; wvr[2][1] = rp2[1]; wvr[2][2] = rp2[2];
            wvr[3][0] = rp3[0]; wvr[3][1] = rp3[1]; wvr[3][2] = rp3[2];
        } else {
            #pragma unroll
            for (int di = 0; di < 4; ++di) {
                const float* row = bxr + (size_t)(i0 + di) * L_ + l0;
                float tmp[12];
                #pragma unroll
                for (int w = 0; w < 12; ++w) {
                    int p = l0 + lb - 4 + w;
                    tmp[w] = (p >= 0 && p < L_) ? row[lb - 4 + w] : 0.f;
                }
                wvr[di][0] = make_float4(tmp[0], tmp[1], tmp[2], tmp[3]);
                wvr[di][1] = make_float4(tmp[4], tmp[5], tmp[6], tmp[7]);
                wvr[di][2] = make_float4(tmp[8], tmp[9], tmp[10], tmp[11]);
            }
        }

        // -- compute phase: unpack + 7-tap conv + bf16 pack --
        u16 hv[4][4];                      // [dl][di]
        #pragma unroll
        for (int di = 0; di < 4; ++di) {
            float x[12];
            x[0]=wvr[di][0].x; x[1]=wvr[di][0].y; x[2]=wvr[di][0].z; x[3]=wvr[di][0].w;
            x[4]=wvr[di][1].x; x[5]=wvr[di][1].y; x[6]=wvr[di][1].z; x[7]=wvr[di][1].w;
            x[8]=wvr[di][2].x; x[9]=wvr[di][2].y; x[10]=wvr[di][2].z; x[11]=wvr[di][2].w;
            #pragma unroll
            for (int dl = 0; dl < 4; ++dl) {
                float a = 0.f;
                #pragma unroll
                for (int j = 0; j < K_; ++j) a += wr[di][j] * x[dl + 1 + j];
                hv[dl][di] = f2bf(a);
            }
        }
        #pragma unroll
        for (int dl = 0; dl < 4; ++dl) {
            int n = lb + dl;
            u32 lo = (u32)hv[dl][0] | ((u32)hv[dl][1] << 16);
            u32 hi = (u32)hv[dl][2] | ((u32)hv[dl][3] << 16);
            *(uint2*)(&Xs[n * LDK + i0]) = make_uint2(lo, hi);
        }
    }
    __syncthreads();

    // ---- Phase 2: GEMM (unchanged from R1 champion) ----
    f32x4 acc[4][4];
    #pragma unroll
    for (int r = 0; r < 4; ++r)
        #pragma unroll
        for (int c = 0; c < 4; ++c)
            acc[r][c] = (f32x4){0.f, 0.f, 0.f, 0.f};

    const u16* Wrow = Wb + (size_t)(b * O_ + wv * 64 + mlane) * I_;

    for (int kb = 0; kb < 8; ++kb) {
        const int koff = kb * 32 + quad * 8;
        short8 a[4], bbf[4];
        #pragma unroll
        for (int r = 0; r < 4; ++r)
            a[r] = *(const short8*)(Wrow + r * 16 * I_ + koff);
        #pragma unroll
        for (int c = 0; c < 4; ++c)
            bbf[c] = *(const short8*)(&Xs[(c * 16 + mlane) * LDK + koff]);
        #pragma unroll
        for (int r = 0; r < 4; ++r)
            #pragma unroll
            for (int c = 0; c < 4; ++c)
                acc[r][c] = __builtin_amdgcn_mfma_f32_16x16x32_bf16(a[r], bbf[c], acc[r][c], 0, 0, 0);
    }

    // ---- Epilogue: + proj_b, store ----
    float* outb = out + (size_t)b * O_ * L_;
    #pragma unroll
    for (int r = 0; r < 4; ++r) {
        const int obase = wv * 64 + r * 16 + quad * 4;
        #pragma unroll
        for (int p = 0; p < 4; ++p) {
            const int o = obase + p;
            const float bias = proj_b[o];
            float* orow = outb + (size_t)o * L_ + l0 + mlane;
            #pragma unroll
            for (int c = 0; c < 4; ++c)
                orow[c * 16] = acc[r][c][p] + bias;
        }
    }
}

extern "C" void kernel_launch(void* const* d_in, const int* in_sizes, int n_in,
                              void* d_out, int out_size, void* d_ws, size_t ws_size,
                              hipStream_t stream) {
    const float* bx     = (const float*)d_in[0];
    const float* t      = (const float*)d_in[1];
    const float* conv_w = (const float*)d_in[2];
    const float* proj_w = (const float*)d_in[3];
    const float* proj_b = (const float*)d_in[4];
    const float* mod_w  = (const float*)d_in[5];
    const float* mod_b  = (const float*)d_in[6];
    float* out = (float*)d_out;

    float* mod = (float*)d_ws;                       // 16 KB
    u16*   Wb  = (u16*)((char*)d_ws + 16384);        // 2 MB bf16 modulated weights

    mod_kernel<<<dim3(16, 16), 256, 0, stream>>>(t, mod_w, mod_b, mod);
    wmod_kernel<<<dim3(16, 16), 256, 0, stream>>>(proj_w, mod, Wb);
    main_kernel<<<dim3(128, 16), 256, 0, stream>>>(bx, conv_w, Wb, proj_b, out);
}

// Round 13
// 303.682 us; speedup vs baseline: 1.2636x; 1.0368x over previous
//
#include <hip/hip_runtime.h>
#include <hip/hip_bf16.h>

#define B_ 16
#define I_ 256
#define O_ 256
#define T_ 512
#define L_ 8192
#define K_ 7
#define PAD_ 3
#define BN 64
#define NTILE 128
#define LDK 264   // Xs row stride in bf16 elements (256 + 8 pad)
#define XFS 77    // Xf row stride in floats: odd -> b32 conv reads hit all 32 banks
#define XFN 9984  // 39*256 staged floats (covers 128*77=9856 + tail pad)

typedef unsigned short u16;
typedef unsigned int u32;
typedef __attribute__((ext_vector_type(8))) short short8;
typedef __attribute__((ext_vector_type(4))) float f32x4;

__device__ inline u16 f2bf(float f) {
    union { float f; u32 u; } v; v.f = f;
    u32 r = v.u + 0x7FFF + ((v.u >> 16) & 1);   // RNE
    return (u16)(r >> 16);
}

// ---------------- Kernel 1: mod[b][i] = t[b,:] . mod_w[i,:] + mod_b[i] ----------------
__global__ void mod_kernel(const float* __restrict__ t, const float* __restrict__ mod_w,
                           const float* __restrict__ mod_b, float* __restrict__ mod) {
    int g = blockIdx.x, b = blockIdx.y;
    int lane = threadIdx.x & 63, wv = threadIdx.x >> 6;
    const float* tb = t + b * T_;
    #pragma unroll
    for (int q = 0; q < 4; ++q) {
        int i = g * 16 + wv * 4 + q;
        const float* wr = mod_w + (size_t)i * T_;
        float s = 0.f;
        #pragma unroll
        for (int u = 0; u < 8; ++u) s += wr[lane + u * 64] * tb[lane + u * 64];
        #pragma unroll
        for (int d = 32; d; d >>= 1) s += __shfl_down(s, d);
        if (lane == 0) mod[b * I_ + i] = s + mod_b[i];
    }
}

// ---------------- Kernel 2: Wb[b][o][i] = bf16( proj_w[o,i]*(mod[b,i]+1) * demod[b,o] ) ----
__global__ void wmod_kernel(const float* __restrict__ proj_w, const float* __restrict__ mod,
                            u16* __restrict__ Wb) {
    int og = blockIdx.x, b = blockIdx.y;
    int lane = threadIdx.x & 63, wv = threadIdx.x >> 6;
    const float* mrow = mod + b * I_;
    #pragma unroll
    for (int q = 0; q < 4; ++q) {
        int o = og * 16 + wv * 4 + q;
        const float* pw = proj_w + (size_t)o * I_;
        float4 pv = *(const float4*)(pw + lane * 4);
        float4 mv = *(const float4*)(mrow + lane * 4);
        float v0 = pv.x * (mv.x + 1.f);
        float v1 = pv.y * (mv.y + 1.f);
        float v2 = pv.z * (mv.z + 1.f);
        float v3 = pv.w * (mv.w + 1.f);
        float ss = v0*v0 + v1*v1 + v2*v2 + v3*v3;
        #pragma unroll
        for (int d = 32; d; d >>= 1) ss += __shfl_xor(ss, d);
        float dem = rsqrtf(ss + 1e-8f);
        u32 lo = (u32)f2bf(v0 * dem) | ((u32)f2bf(v1 * dem) << 16);
        u32 hi = (u32)f2bf(v2 * dem) | ((u32)f2bf(v3 * dem) << 16);
        *(uint2*)(Wb + (size_t)(b * O_ + o) * I_ + lane * 4) = make_uint2(lo, hi);
    }
}

// ---------------- Kernel 3: fused conv + GEMM, async-DMA-staged conv inputs ----------------
// Per block (64-l tile, one b): 2 channel-chunks of 128.
//   stage:  global_load_lds width-4 streams raw f32 bx rows (cols l0-4..l0+72, clamped)
//           into Xf[ch*77+col] -- ~40KB async in flight, ONE drain at the barrier.
//           (R11 lesson: compiler re-serializes VGPR-destined loads; DMA loads it cannot.)
//   conv:   1 channel/thread from LDS (stride 77 -> conflict-free b32), 'same' padding via
//           edge zero-fix; bf16 results to Xs in GEMM B-frag layout.
//   GEMM:   unchanged R1 champion (16x16x32 MFMA, A-frags from L2-resident Wb).
// LDS 72KB -> 2 blocks/CU: block A's DMA stream overlaps block B's conv/GEMM/stores.
__global__ __launch_bounds__(256) void main_kernel(
    const float* __restrict__ bx, const float* __restrict__ conv_w,
    const u16* __restrict__ Wb, const float* __restrict__ proj_b,
    float* __restrict__ out)
{
    __shared__ __align__(16) float Xf[XFN];       // 39,936 B
    __shared__ __align__(16) u16 Xs[BN * LDK];    // 33,792 B

    const int tile = blockIdx.x;
    const int b = blockIdx.y;
    const int l0 = tile * BN;
    const int tid = threadIdx.x;
    const int lane = tid & 63;
    const int wv = tid >> 6;
    const int mlane = lane & 15;
    const int quad = lane >> 4;
    const float* bxr = bx + (size_t)b * I_ * L_;

    const int ch_init = tid / XFS;
    const int col_init = tid - ch_init * XFS;

    for (int ck = 0; ck < 2; ++ck) {
        const int ci0 = ck << 7;   // 0 or 128

        // ---- async stage: Xf[ch*77+col] = bx[ci0+ch][clamp(l0-4+col)] ----
        {
            int ch = ch_init, col = col_init;
            #pragma unroll
            for (int k = 0; k < 39; ++k) {
                int chc = ch < 127 ? ch : 127;               // tail pad rows -> safe dup
                int p = l0 - 4 + col;
                p = p < 0 ? 0 : (p > L_ - 1 ? L_ - 1 : p);   // clamp; edges fixed below
                const float* gp = bxr + (size_t)(ci0 + chc) * L_ + p;
                __builtin_amdgcn_global_load_lds(
                    (const __attribute__((address_space(1))) u32*)gp,
                    (__attribute__((address_space(3))) u32*)&Xf[k * 256 + tid], 4, 0, 0);
                ch += 3; col += 25;                          // f += 256 (256 = 3*77 + 25)
                if (col >= XFS) { col -= XFS; ch += 1; }
            }
        }
        __syncthreads();   // drains vmcnt: all DMA landed

        // ---- edge zero-fix ('same' padding semantics) ----
        if (tile == 0) {
            for (int z = tid; z < 128 * 4; z += 256)
                Xf[(z >> 2) * XFS + (z & 3)] = 0.f;          // cols 0..3 <=> l = -4..-1
            __syncthreads();
        } else if (tile == NTILE - 1) {
            for (int z = tid; z < 128 * 9; z += 256) {
                int r = z / 9;
                Xf[r * XFS + 68 + (z - r * 9)] = 0.f;        // cols 68..76 <=> l >= 8192
            }
            __syncthreads();
        }

        // ---- conv from LDS: thread = (channel chl, l-half a) ----
        {
            const int chl = tid & 127;
            const int a = (tid >> 7) << 5;                   // 0 or 32
            const int ig = ci0 + chl;
            float w[K_];
            #pragma unroll
            for (int j = 0; j < K_; ++j) w[j] = conv_w[ig * K_ + j];
            const float* xr = &Xf[chl * XFS + a];            // col a+m at xr[m]
            float x[39];
            #pragma unroll
            for (int m = 1; m <= 38; ++m) x[m] = xr[m];      // cols a+1 .. a+38
            #pragma unroll
            for (int n = 0; n < 32; ++n) {                   // output l = l0 + a + n
                float s = 0.f;
                #pragma unroll
                for (int j = 0; j < K_; ++j) s += w[j] * x[n + 1 + j];
                Xs[(a + n) * LDK + ig] = f2bf(s);
            }
        }
        __syncthreads();   // guards next chunk's Xf overwrite / GEMM's Xs reads
    }

    // ---- Phase 2: GEMM (unchanged R1 champion) ----
    f32x4 acc[4][4];
    #pragma unroll
    for (int r = 0; r < 4; ++r)
        #pragma unroll
        for (int c = 0; c < 4; ++c)
            acc[r][c] = (f32x4){0.f, 0.f, 0.f, 0.f};

    const u16* Wrow = Wb + (size_t)(b * O_ + wv * 64 + mlane) * I_;

    for (int kb = 0; kb < 8; ++kb) {
        const int koff = kb * 32 + quad * 8;
        short8 a[4], bbf[4];
        #pragma unroll
        for (int r = 0; r < 4; ++r)
            a[r] = *(const short8*)(Wrow + r * 16 * I_ + koff);
        #pragma unroll
        for (int c = 0; c < 4; ++c)
            bbf[c] = *(const short8*)(&Xs[(c * 16 + mlane) * LDK + koff]);
        #pragma unroll
        for (int r = 0; r < 4; ++r)
            #pragma unroll
            for (int c = 0; c < 4; ++c)
                acc[r][c] = __builtin_amdgcn_mfma_f32_16x16x32_bf16(a[r], bbf[c], acc[r][c], 0, 0, 0);
    }

    // ---- Epilogue: + proj_b, store ----
    float* outb = out + (size_t)b * O_ * L_;
    #pragma unroll
    for (int r = 0; r < 4; ++r) {
        const int obase = wv * 64 + r * 16 + quad * 4;
        #pragma unroll
        for (int p = 0; p < 4; ++p) {
            const int o = obase + p;
            const float bias = proj_b[o];
            float* orow = outb + (size_t)o * L_ + l0 + mlane;
            #pragma unroll
            for (int c = 0; c < 4; ++c)
                orow[c * 16] = acc[r][c][p] + bias;
        }
    }
}

extern "C" void kernel_launch(void* const* d_in, const int* in_sizes, int n_in,
                              void* d_out, int out_size, void* d_ws, size_t ws_size,
                              hipStream_t stream) {
    const float* bx     = (const float*)d_in[0];
    const float* t      = (const float*)d_in[1];
    const float* conv_w = (const float*)d_in[2];
    const float* proj_w = (const float*)d_in[3];
    const float* proj_b = (const float*)d_in[4];
    const float* mod_w  = (const float*)d_in[5];
    const float* mod_b  = (const float*)d_in[6];
    float* out = (float*)d_out;

    float* mod = (float*)d_ws;                       // 16 KB
    u16*   Wb  = (u16*)((char*)d_ws + 16384);        // 2 MB bf16 modulated weights

    mod_kernel<<<dim3(16, 16), 256, 0, stream>>>(t, mod_w, mod_b, mod);
    wmod_kernel<<<dim3(16, 16), 256, 0, stream>>>(proj_w, mod, Wb);
    main_kernel<<<dim3(128, 16), 256, 0, stream>>>(bx, conv_w, Wb, proj_b, out);
}